// Round 2
// baseline (153.070 us; speedup 1.0000x reference)
//
#include <hip/hip_runtime.h>

// Bidirectional LSTM, B=16384 T=512 I=1 H=8, + final linear on [h_f(T-1), h_b(T-1)].
// Backward direction's state at time T-1 is its FIRST scan step -> one step only.
//
// R2 decomposition: 16 lanes per batch element (4 waves/SIMD instead of 2, to
// hide the per-step swizzle+dependency latency chain).
//   lane l, j = l&7:  l<8  owns gate rows j (i) and 8+j (f)   -> sigmoid both
//                     l>=8 owns gate rows 16+j (g) and 24+j (o) -> tanh, sigmoid
// Per step: broadcast h (8 swizzles from low half), 18 FMA (2 gate dots), apply
// activations (uniform code via per-lane (mA,sA,oA) constants), 2 cross swizzles
// to pull tanh(g)/sig(o) down to the low half, then c/h update on all lanes
// (high half computes garbage c/h that is never read -- h is re-broadcast from
// the low half each step).

#define LOG2E 1.4426950408889634f

#define SWZ(v, imm) __int_as_float(__builtin_amdgcn_ds_swizzle(__float_as_int(v), (imm)))
// broadcast lane (group16_base | k) to all 16 lanes of the group
#define BC16(v, k) SWZ(v, ((k) << 5) | 0x10)
// pull from the high 8-lane half of the 16-group: src = (i & 0x17) | 8
#define XHI(v) SWZ(v, (8 << 5) | 0x17)

struct LaneCtx {
    float wA[8], wB[8];
    float wxA, wxB, bA, bB;
    float mA, sA, oA;  // activation for row A: a = fma(rcp(1+exp2(z*mA)), sA, oA)
};

__device__ __forceinline__ void load_ctx(LaneCtx& L, int l, int j,
    const float* __restrict__ w_ih, const float* __restrict__ w_hh,
    const float* __restrict__ b)
{
    int rowA = (l < 8) ? j : (16 + j);
    int rowB = rowA + 8;
    const float4* whh = (const float4*)w_hh;
    *(float4*)&L.wA[0] = whh[2 * rowA];
    *(float4*)&L.wA[4] = whh[2 * rowA + 1];
    *(float4*)&L.wB[0] = whh[2 * rowB];
    *(float4*)&L.wB[4] = whh[2 * rowB + 1];
    L.wxA = w_ih[rowA]; L.wxB = w_ih[rowB];
    L.bA = b[rowA];     L.bB = b[rowB];
    if (l < 8) { L.mA = -LOG2E;        L.sA = 1.0f; L.oA = 0.0f; }   // sigmoid(i)
    else       { L.mA = -2.0f * LOG2E; L.sA = 2.0f; L.oA = -1.0f; }  // tanh(g)
}

__device__ __forceinline__ void step16(float xt, float& h, float& c, const LaneCtx& L)
{
    float hk[8];
    hk[0] = BC16(h, 0); hk[1] = BC16(h, 1);
    hk[2] = BC16(h, 2); hk[3] = BC16(h, 3);
    hk[4] = BC16(h, 4); hk[5] = BC16(h, 5);
    hk[6] = BC16(h, 6); hk[7] = BC16(h, 7);

    float zA = fmaf(xt, L.wxA, L.bA);
    float zB = fmaf(xt, L.wxB, L.bB);
#pragma unroll
    for (int k = 0; k < 8; ++k) {
        zA = fmaf(hk[k], L.wA[k], zA);
        zB = fmaf(hk[k], L.wB[k], zB);
    }

    // row A activation: low = sigmoid(i), high = tanh(g)
    float eA = __builtin_amdgcn_exp2f(zA * L.mA);
    float aA = fmaf(__builtin_amdgcn_rcpf(1.0f + eA), L.sA, L.oA);
    // row B activation: sigmoid (f on low, o on high)
    float eB = __builtin_amdgcn_exp2f(zB * (-LOG2E));
    float aB = __builtin_amdgcn_rcpf(1.0f + eB);

    // bring tanh(g) and sig(o) down to the low half (high lanes read themselves)
    float tg = XHI(aA);
    float so = XHI(aB);

    // low lanes: c = sig(f)*c + sig(i)*tanh(g); h = sig(o)*tanh(c)
    c = fmaf(aB, c, aA * tg);
    float ec = __builtin_amdgcn_exp2f(c * (-2.0f * LOG2E));
    float tc = fmaf(2.0f, __builtin_amdgcn_rcpf(1.0f + ec), -1.0f);
    h = so * tc;
}

__global__ __launch_bounds__(256, 4) void bilstm_kernel(
    const float* __restrict__ x, const float* __restrict__ h0, const float* __restrict__ c0,
    const float* __restrict__ w_ih_f, const float* __restrict__ w_hh_f, const float* __restrict__ b_f,
    const float* __restrict__ w_ih_b, const float* __restrict__ w_hh_b, const float* __restrict__ b_b,
    const float* __restrict__ w_lin, const float* __restrict__ b_lin,
    float* __restrict__ out, int B, int T)
{
    int tid = blockIdx.x * 256 + threadIdx.x;
    int b = tid >> 4;
    int l = tid & 15;
    int j = l & 7;
    if (b >= B) return;

    LaneCtx Lf;
    load_ctx(Lf, l, j, w_ih_f, w_hh_f, b_f);

    float h = h0[(size_t)b * 8 + j];
    float c = c0[(size_t)b * 8 + j];

    const float4* xr = (const float4*)(x + (size_t)b * T);
    int nT4 = T >> 2;
    for (int t4 = 0; t4 < nT4; ++t4) {
        float4 xv = xr[t4];
        step16(xv.x, h, c, Lf);
        step16(xv.y, h, c, Lf);
        step16(xv.z, h, c, Lf);
        step16(xv.w, h, c, Lf);
    }

    // backward direction: exactly one step on x[:, T-1]
    LaneCtx Lb;
    load_ctx(Lb, l, j, w_ih_b, w_hh_b, b_b);
    float hb = h0[(size_t)B * 8 + (size_t)b * 8 + j];
    float cb = c0[(size_t)B * 8 + (size_t)b * 8 + j];
    float xlast = x[(size_t)b * T + (T - 1)];
    step16(xlast, hb, cb, Lb);

    // final linear: out[b] = sum_j h[j]*wl[j] + hb[j]*wl[8+j] + b_lin
    float part = (l < 8) ? fmaf(h, w_lin[j], hb * w_lin[8 + j]) : 0.0f;
    part += __shfl_xor(part, 1, 8);
    part += __shfl_xor(part, 2, 8);
    part += __shfl_xor(part, 4, 8);
    if (l == 0) out[b] = part + b_lin[0];
}

extern "C" void kernel_launch(void* const* d_in, const int* in_sizes, int n_in,
                              void* d_out, int out_size, void* d_ws, size_t ws_size,
                              hipStream_t stream)
{
    const float* x      = (const float*)d_in[0];
    const float* h0     = (const float*)d_in[1];
    const float* c0     = (const float*)d_in[2];
    const float* w_ih_f = (const float*)d_in[3];
    const float* w_hh_f = (const float*)d_in[4];
    const float* b_f    = (const float*)d_in[5];
    const float* w_ih_b = (const float*)d_in[6];
    const float* w_hh_b = (const float*)d_in[7];
    const float* b_b    = (const float*)d_in[8];
    const float* w_lin  = (const float*)d_in[9];
    const float* b_lin  = (const float*)d_in[10];
    float* out = (float*)d_out;

    int B = in_sizes[1] / 16;   // h0: (2, B, 8)
    int T = in_sizes[0] / B;    // x:  (B, T, 1)

    int threads = B * 16;
    dim3 block(256);
    dim3 grid((threads + 255) / 256);
    hipLaunchKernelGGL(bilstm_kernel, grid, block, 0, stream,
                       x, h0, c0, w_ih_f, w_hh_f, b_f, w_ih_b, w_hh_b, b_b,
                       w_lin, b_lin, out, B, T);
}